// Round 6
// baseline (293.103 us; speedup 1.0000x reference)
//
#include <hip/hip_runtime.h>

// x        [64, 524288] f32 | idx_feat [4096,256] f32 | weight [64,256] f32
// bias     [64] f32         | pred_cate [4096] i32    | pred_score [4096] f32
// out (f32 concat): seg_pred [53*524288], unique_cate [53], fused_score [53]

#define KK   4096
#define CIN  256
#define CC   64
#define HW   524288   // 512*1024
#define HW4  (HW / 4) // float4 columns
#define UU   53
#define FWS  56       // fwt row stride (53 padded)

#define CH   64            // partial-sum chunks (blocks)
#define RPB  (KK / CH)     // 64 rows per chunk
#define TBL  (UU * CIN)    // 13568 floats per partial table

// ws layout (floats): partials [CH][TBL], then fwt [64][FWS]
#define WS_PART 0
#define WS_FWT  (CH * TBL)     // 868352 (3.47 MB) -- all fully overwritten

typedef float f4 __attribute__((ext_vector_type(4)));

// ---------------------------------------------------------------------------
// Stage 1: per-chunk partial segment sums. 64 blocks x 64 rows; thread tid
// exclusively owns LDS column {cls*256+tid} (no races, deterministic, no
// atomics, no memset needed). LDS 54.3 KB; 2-way bank aliasing only (free).
// ---------------------------------------------------------------------------
__global__ __launch_bounds__(256)
void partial_kernel(const float* __restrict__ idx_feat,
                    const int*   __restrict__ pred_cate,
                    float* __restrict__ ws)
{
    __shared__ float s[TBL];
    const int tid = threadIdx.x, blk = blockIdx.x;

    for (int i = tid; i < TBL; i += 256) s[i] = 0.0f;
    __syncthreads();

    const int k0 = blk * RPB;
    #pragma unroll 4
    for (int r = 0; r < RPB; ++r) {
        const int cls = pred_cate[k0 + r];                    // wave-uniform
        s[cls * CIN + tid] += idx_feat[(size_t)(k0 + r) * CIN + tid];
    }
    __syncthreads();

    float* dst = ws + WS_PART + (size_t)blk * TBL;
    for (int i = tid; i < TBL; i += 256) dst[i] = s[i];
}

// ---------------------------------------------------------------------------
// Stage 2: finalize. One block per class u, 256 threads:
//  - reduce 64 partials (coalesced, all 64 loads in flight)
//  - score/count via strided scan + LDS tree
//  - projection split 4-way: thread (c=tid>>2, q=tid&3) does a 64-long
//    quarter dot-product, LDS combine -> fwt[c][u] (TRANSPOSED, stride FWS)
// ---------------------------------------------------------------------------
__global__ __launch_bounds__(256)
void finalize_kernel(const float* __restrict__ ws_ro,
                     const float* __restrict__ weight,
                     const float* __restrict__ bias,
                     const int*   __restrict__ pred_cate,
                     const float* __restrict__ pred_score,
                     float* __restrict__ ws,
                     float* __restrict__ out)
{
    __shared__ float sf[CIN];
    __shared__ float rp[256];
    __shared__ float rs[256], rc[256];
    const int u = blockIdx.x, tid = threadIdx.x;

    float v = 0.0f;
    #pragma unroll
    for (int b = 0; b < CH; ++b)
        v += ws_ro[WS_PART + (size_t)b * TBL + u * CIN + tid];
    sf[tid] = v;

    float sc = 0.0f, cnt = 0.0f;
    #pragma unroll
    for (int k = tid; k < KK; k += 256)
        if (pred_cate[k] == u) { sc += pred_score[k]; cnt += 1.0f; }
    rs[tid] = sc; rc[tid] = cnt;
    __syncthreads();
    for (int step = 128; step > 0; step >>= 1) {
        if (tid < step) { rs[tid] += rs[tid + step]; rc[tid] += rc[tid + step]; }
        __syncthreads();
    }
    const float inv = 1.0f / rc[0];

    const int c = tid >> 2, q = tid & 3;
    float d = 0.0f;
    #pragma unroll 8
    for (int i = q * 64; i < q * 64 + 64; ++i)
        d = fmaf(sf[i], weight[(size_t)c * CIN + i], d);
    rp[tid] = d;
    __syncthreads();

    if (tid < CC) {
        const float t = rp[tid * 4] + rp[tid * 4 + 1] + rp[tid * 4 + 2] + rp[tid * 4 + 3];
        ws[WS_FWT + tid * FWS + u] = t * inv + bias[tid];
    }
    if (tid == 0) {
        out[(size_t)UU * HW + u]      = (float)u;          // unique_cate
        out[(size_t)UU * HW + UU + u] = rs[0] * inv;       // fused_score
    }
}

// ---------------------------------------------------------------------------
// Stage 3: seg_pred = fw [53,64] @ x [64, HW].
// Thread owns one float4 column; all 53 f4 accumulators in registers
// (212 VGPR, launch_bounds(256,2) -> 2 waves/SIMD = 512 co-resident blocks).
// Manual 2-deep software pipeline: next channel-pair loads issued BEFORE the
// current 848-cyc FMA block -> ~900-cyc nt-HBM latency fully hidden (the R5
// unroll-2 body had zero loads in flight during compute). x/out are pure
// streams -> non-temporal, bypass L2. fwt rows are 53 consecutive uniform
// floats -> batched s_loads. Floors: mem 242 MB @6.3 TB/s = 38.5 us.
// ---------------------------------------------------------------------------
__device__ __forceinline__
void fma53(f4* acc, const float* __restrict__ fwt_row, const f4 xv)
{
    #pragma unroll
    for (int u = 0; u < UU; ++u) {
        const float w = fwt_row[u];                 // wave-uniform, consecutive
        acc[u].x = fmaf(w, xv.x, acc[u].x);
        acc[u].y = fmaf(w, xv.y, acc[u].y);
        acc[u].z = fmaf(w, xv.z, acc[u].z);
        acc[u].w = fmaf(w, xv.w, acc[u].w);
    }
}

__global__ __launch_bounds__(256, 2)
void seg_pred_kernel(const float* __restrict__ x,
                     const float* __restrict__ ws,
                     float* __restrict__ out)
{
    const int j = blockIdx.x * 256 + threadIdx.x;   // float4 column index
    const f4* x4   = (const f4*)x;
    f4*       out4 = (f4*)out;
    const float* fwt = ws + WS_FWT;

    f4 acc[UU];
    #pragma unroll
    for (int u = 0; u < UU; ++u) acc[u] = (f4)0.0f;

    f4 xa = __builtin_nontemporal_load(&x4[j]);
    f4 xb = __builtin_nontemporal_load(&x4[(size_t)HW4 + j]);

    #pragma unroll 1
    for (int c = 0; c < CC - 2; c += 2) {
        const f4 xn0 = __builtin_nontemporal_load(&x4[(size_t)(c + 2) * HW4 + j]);
        const f4 xn1 = __builtin_nontemporal_load(&x4[(size_t)(c + 3) * HW4 + j]);
        fma53(acc, fwt + c * FWS,       xa);
        fma53(acc, fwt + (c + 1) * FWS, xb);
        xa = xn0; xb = xn1;
    }
    fma53(acc, fwt + (CC - 2) * FWS, xa);
    fma53(acc, fwt + (CC - 1) * FWS, xb);

    #pragma unroll
    for (int u = 0; u < UU; ++u)
        __builtin_nontemporal_store(acc[u], &out4[(size_t)u * HW4 + j]);
}

extern "C" void kernel_launch(void* const* d_in, const int* in_sizes, int n_in,
                              void* d_out, int out_size, void* d_ws, size_t ws_size,
                              hipStream_t stream)
{
    const float* x          = (const float*)d_in[0];
    const float* idx_feat   = (const float*)d_in[1];
    const float* weight     = (const float*)d_in[2];
    const float* bias       = (const float*)d_in[3];
    const int*   pred_cate  = (const int*)d_in[4];
    const float* pred_score = (const float*)d_in[5];

    float* out = (float*)d_out;
    float* ws  = (float*)d_ws;

    partial_kernel<<<CH, 256, 0, stream>>>(idx_feat, pred_cate, ws);
    finalize_kernel<<<UU, 256, 0, stream>>>(ws, weight, bias,
                                            pred_cate, pred_score, ws, out);
    seg_pred_kernel<<<HW4 / 256, 256, 0, stream>>>(x, ws, out);  // 512 blocks
}